// Round 5
// baseline (441.613 us; speedup 1.0000x reference)
//
#include <hip/hip_runtime.h>

// Focal loss: N=1048576 rows, C=80 classes, fp32 input, int target, scalar mean.
// HBM-bound streaming: 344 MB read once -> ~52 us floor at 6.6 TB/s (measured via
// harness fill dispatches). VALU analysis: ~160 cyc/SIMD per wave-iter vs ~3150 cyc
// HBM time per 32-wave iteration batch -> 2.4x compute headroom, memory-bound.
// This revision: unroll 8 (8 outstanding global_load_dwordx4/thread) to falsify
// the latency-hiding hypothesis; predicted neutral if already at BW floor.
// (R4 was an infra failure — identical kernel resubmitted.)

#define FL_N      1048576
#define FL_C      80
#define FL_NVEC   (FL_N * FL_C / 4)        // 20,971,520 float4s
#define FL_BLOCKS 2048
#define FL_TPB    256
#define FL_STRIDE (FL_BLOCKS * FL_TPB)     // 524,288 threads
#define FL_ITERS  (FL_NVEC / FL_STRIDE)    // exactly 40

// Native clang vector (HIP float4 is a class — nontemporal builtin rejects it).
typedef float floatx4 __attribute__((ext_vector_type(4)));

__global__ __launch_bounds__(FL_TPB) void focal_loss_kernel(
    const float* __restrict__ inp,
    const int* __restrict__ tgt,
    float* __restrict__ out)
{
    const floatx4* inp4 = reinterpret_cast<const floatx4*>(inp);
    const int f0 = blockIdx.x * FL_TPB + threadIdx.x;

    float acc0 = 0.0f, acc1 = 0.0f;        // two chains for fma-latency ILP

    #pragma unroll 8
    for (int i = 0; i < FL_ITERS; ++i) {
        int f = f0 + i * FL_STRIDE;
        floatx4 v = __builtin_nontemporal_load(&inp4[f]); // streaming: no reuse
        int r  = f / 20;                    // row (magic-mul)
        int dt = tgt[r] - (f - r * 20) * 4; // target's k within this vec4 (hit iff 0..3)

        #pragma unroll
        for (int k = 0; k < 4; ++k) {
            // nx = -x: -v at target class, +v elsewhere
            float nx = (k == dt) ? -v[k] : v[k];
            float u  = __expf(nx);
            float d  = 1.0f + u;
            float rc = __builtin_amdgcn_rcpf(d);   // 1/d
            float lg = __logf(d);                  // -logpt >= 0
            float w  = u * rc;                     // 1 - pt
            if (k & 1) acc1 = fmaf(w * w, lg, acc1);
            else       acc0 = fmaf(w * w, lg, acc0);
        }
    }

    float acc = acc0 + acc1;

    // 64-lane wave shuffle reduction
    #pragma unroll
    for (int off = 32; off > 0; off >>= 1)
        acc += __shfl_down(acc, off, 64);

    __shared__ float ws[4];                 // 256 threads = 4 waves
    if ((threadIdx.x & 63) == 0) ws[threadIdx.x >> 6] = acc;
    __syncthreads();
    if (threadIdx.x == 0) {
        float s = ws[0] + ws[1] + ws[2] + ws[3];
        atomicAdd(out, s * (1.0f / (float)FL_N));   // one atomic per block
    }
}

extern "C" void kernel_launch(void* const* d_in, const int* in_sizes, int n_in,
                              void* d_out, int out_size, void* d_ws, size_t ws_size,
                              hipStream_t stream) {
    const float* inp = (const float*)d_in[0];
    const int*   tgt = (const int*)d_in[1];
    float*       out = (float*)d_out;

    // d_out is poisoned 0xAA before every timed launch — zero it (capture-safe).
    (void)hipMemsetAsync(out, 0, sizeof(float), stream);

    focal_loss_kernel<<<dim3(FL_BLOCKS), dim3(FL_TPB), 0, stream>>>(inp, tgt, out);
}